// Round 1
// baseline (319.840 us; speedup 1.0000x reference)
//
#include <hip/hip_runtime.h>
#include <math.h>

#define BB 32
#define TT 2048
#define DD 1024
#define NH 16
#define HDIM 64
#define EPS 1e-5f
#define NC 8
#define CT (TT/NC)

// ---------------- reduction helpers ----------------
__device__ __forceinline__ float wredSum(float v){
  v += __shfl_down(v, 32, 64);
  v += __shfl_down(v, 16, 64);
  v += __shfl_down(v, 8, 64);
  v += __shfl_down(v, 4, 64);
  v += __shfl_down(v, 2, 64);
  v += __shfl_down(v, 1, 64);
  return v;
}
__device__ __forceinline__ float wredMax(float v){
  v = fmaxf(v, __shfl_down(v, 32, 64));
  v = fmaxf(v, __shfl_down(v, 16, 64));
  v = fmaxf(v, __shfl_down(v, 8, 64));
  v = fmaxf(v, __shfl_down(v, 4, 64));
  v = fmaxf(v, __shfl_down(v, 2, 64));
  v = fmaxf(v, __shfl_down(v, 1, 64));
  return v;
}
__device__ float bredSum(float v, float* red){
  int lane = threadIdx.x & 63, w = threadIdx.x >> 6, nw = blockDim.x >> 6;
  v = wredSum(v);
  __syncthreads();
  if (lane == 0) red[w] = v;
  __syncthreads();
  if (w == 0){
    float x = (lane < nw) ? red[lane] : 0.f;
    x = wredSum(x);
    if (lane == 0) red[0] = x;
  }
  __syncthreads();
  return red[0];
}
__device__ float bredMax(float v, float* red){
  int lane = threadIdx.x & 63, w = threadIdx.x >> 6, nw = blockDim.x >> 6;
  v = wredMax(v);
  __syncthreads();
  if (lane == 0) red[w] = v;
  __syncthreads();
  if (w == 0){
    float x = (lane < nw) ? red[lane] : -1e30f;
    x = wredMax(x);
    if (lane == 0) red[0] = x;
  }
  __syncthreads();
  return red[0];
}

// ---------------- K0a: q = LN(h_t)*tau ----------------
__global__ __launch_bounds__(256) void k_qln(const float* __restrict__ h_t,
   const float* __restrict__ g, const float* __restrict__ bb,
   const float* __restrict__ log_tau, float* __restrict__ q)
{
  int b = blockIdx.x, tid = threadIdx.x;
  __shared__ float red[64];
  float4 x = ((const float4*)(h_t + (size_t)b*DD))[tid];
  float s = x.x + x.y + x.z + x.w;
  s = bredSum(s, red);
  float mu = s * (1.f/DD);
  float d0=x.x-mu, d1=x.y-mu, d2=x.z-mu, d3=x.w-mu;
  float s2 = d0*d0 + d1*d1 + d2*d2 + d3*d3;
  s2 = bredSum(s2, red);
  float rs = rsqrtf(s2*(1.f/DD) + EPS);
  float tau = fminf(fmaxf(expf(log_tau[0]), 0.25f), 4.0f);
  float4 gv = ((const float4*)g)[tid], bv = ((const float4*)bb)[tid];
  float4 o;
  o.x = (d0*rs*gv.x + bv.x)*tau;
  o.y = (d1*rs*gv.y + bv.y)*tau;
  o.z = (d2*rs*gv.z + bv.z)*tau;
  o.w = (d3*rs*gv.w + bv.w)*tau;
  ((float4*)(q + (size_t)b*DD))[tid] = o;
}

// ------------- small GEMM (32x1024 @ 1024x1024^T), d-split partials -------------
// grid (16 e-chunks, 8 d-splits), 256 threads
__global__ __launch_bounds__(256) void k_gemmsplit(const float* __restrict__ A,
    const float* __restrict__ W, float* __restrict__ p2)
{
  int ec = blockIdx.x, ds = blockIdx.y;
  int tid = threadIdx.x;
  __shared__ float Wl[64][132];
  __shared__ float Al[32][132];
  int d0 = ds*128, e0 = ec*64;
#pragma unroll
  for (int p=0;p<8;p++){
    int fi = p*256 + tid, r = fi >> 5, q4 = fi & 31;
    float4 v = *(const float4*)(W + (size_t)(e0+r)*DD + d0 + q4*4);
    *(float4*)&Wl[r][q4*4] = v;   // 132*4=528 bytes row stride, 16B aligned
  }
#pragma unroll
  for (int p=0;p<4;p++){
    int fi = p*256 + tid, r = fi >> 5, q4 = fi & 31;
    float4 v = *(const float4*)(A + (size_t)r*DD + d0 + q4*4);
    *(float4*)&Al[r][q4*4] = v;
  }
  __syncthreads();
  int eL = tid & 63, bg = tid >> 6;
  float acc[8];
#pragma unroll
  for (int i=0;i<8;i++) acc[i]=0.f;
  for (int d4=0; d4<32; d4++){
    float4 w = *(float4*)&Wl[eL][d4*4];
#pragma unroll
    for (int i=0;i<8;i++){
      float4 a = *(float4*)&Al[bg*8+i][d4*4];
      acc[i] = fmaf(w.x, a.x, acc[i]);
      acc[i] = fmaf(w.y, a.y, acc[i]);
      acc[i] = fmaf(w.z, a.z, acc[i]);
      acc[i] = fmaf(w.w, a.w, acc[i]);
    }
  }
#pragma unroll
  for (int i=0;i<8;i++)
    p2[((size_t)ds*BB + (bg*8+i))*DD + e0 + eL] = acc[i];
}

__global__ __launch_bounds__(256) void k_gemmred(const float* __restrict__ p2,
    const float* __restrict__ bias, float* __restrict__ out)
{
  int b = blockIdx.x, tid = threadIdx.x;
  int e = tid*4;
  float4 s = make_float4(0.f,0.f,0.f,0.f);
#pragma unroll
  for (int ds=0; ds<8; ds++){
    float4 v = *(const float4*)(p2 + ((size_t)ds*BB + b)*DD + e);
    s.x+=v.x; s.y+=v.y; s.z+=v.z; s.w+=v.w;
  }
  float4 bv = *(const float4*)(bias + e);
  s.x+=bv.x; s.y+=bv.y; s.z+=bv.z; s.w+=bv.w;
  *(float4*)(out + (size_t)b*DD + e) = s;
}

// ------------- K0c: s = Wk_h^T qh_h ; gs_t, gsum, cst -------------
// grid (NH, B), 256 threads
__global__ __launch_bounds__(256) void k_prep_s(const float* __restrict__ qh,
    const float* __restrict__ Wfull, const float* __restrict__ bfull,
    const float* __restrict__ g_kv, const float* __restrict__ b_kv,
    float* __restrict__ gs_t, float* __restrict__ gsum, float* __restrict__ cst)
{
  int h = blockIdx.x, b = blockIdx.y;
  int tid = threadIdx.x;
  __shared__ float qhl[64];
  __shared__ float red[64];
  if (tid < 64) qhl[tid] = qh[(size_t)b*DD + h*HDIM + tid];
  __syncthreads();
  float lgs = 0.f, lbs = 0.f;
  const float* Wk = Wfull + (size_t)DD*DD;
#pragma unroll 1
  for (int d = tid; d < DD; d += 256){
    float s = 0.f;
#pragma unroll 8
    for (int j=0;j<64;j++)
      s = fmaf(Wk[(size_t)(h*HDIM+j)*DD + d], qhl[j], s);
    float gsv = s * g_kv[d];
    gs_t[((size_t)b*DD + d)*NH + h] = gsv;
    lgs += gsv;
    lbs = fmaf(s, b_kv[d], lbs);
  }
  float lc = 0.f;
  if (tid < 64) lc = qhl[tid] * bfull[DD + h*HDIM + tid];
  float tg = bredSum(lgs, red);
  float tb = bredSum(lbs + lc, red);
  if (tid == 0){ gsum[b*NH+h] = tg; cst[b*NH+h] = tb; }
}

// ------------- K1: fused row-stats + scores -------------
// grid (T/128, B), 128 threads; lane owns one t-row
__global__ __launch_bounds__(128) void k_scores(
    const float* __restrict__ X, const int* __restrict__ valid,
    const float* __restrict__ gs_t, const float* __restrict__ gsum,
    const float* __restrict__ cst, float* __restrict__ scores,
    float* __restrict__ mu_a, float* __restrict__ rs_a)
{
  int tc = blockIdx.x, b = blockIdx.y;
  int t0 = tc * 128;
  if (t0 >= valid[b]) return;
  int tid = threadIdx.x;
  int row = tid;
  __shared__ float tile[128][33];
  float acc[16];
#pragma unroll
  for (int h=0;h<16;h++) acc[h]=0.f;
  float ssum = 0.f, ssq = 0.f;
  const float* xb = X + ((size_t)b*TT + t0)*DD;
  for (int dc=0; dc<DD; dc+=32){
#pragma unroll
    for (int p=0;p<8;p++){
      int fi = p*128 + tid;
      int r = fi >> 3, q4 = fi & 7;
      float4 v = *(const float4*)(xb + (size_t)r*DD + dc + q4*4);
      tile[r][q4*4+0]=v.x; tile[r][q4*4+1]=v.y;
      tile[r][q4*4+2]=v.z; tile[r][q4*4+3]=v.w;
    }
    __syncthreads();
    const float* gsp = gs_t + ((size_t)b*DD + dc)*NH;
#pragma unroll 2
    for (int d=0; d<32; d++){
      float xv = tile[row][d];
      ssum += xv;
      ssq = fmaf(xv, xv, ssq);
      const float4* gh = (const float4*)(gsp + d*NH);
      float4 g0 = gh[0], g1 = gh[1], g2 = gh[2], g3 = gh[3];
      acc[0]=fmaf(xv,g0.x,acc[0]);  acc[1]=fmaf(xv,g0.y,acc[1]);
      acc[2]=fmaf(xv,g0.z,acc[2]);  acc[3]=fmaf(xv,g0.w,acc[3]);
      acc[4]=fmaf(xv,g1.x,acc[4]);  acc[5]=fmaf(xv,g1.y,acc[5]);
      acc[6]=fmaf(xv,g1.z,acc[6]);  acc[7]=fmaf(xv,g1.w,acc[7]);
      acc[8]=fmaf(xv,g2.x,acc[8]);  acc[9]=fmaf(xv,g2.y,acc[9]);
      acc[10]=fmaf(xv,g2.z,acc[10]); acc[11]=fmaf(xv,g2.w,acc[11]);
      acc[12]=fmaf(xv,g3.x,acc[12]); acc[13]=fmaf(xv,g3.y,acc[13]);
      acc[14]=fmaf(xv,g3.z,acc[14]); acc[15]=fmaf(xv,g3.w,acc[15]);
    }
    __syncthreads();
  }
  float mu = ssum * (1.f/DD);
  float var = ssq*(1.f/DD) - mu*mu;
  float rs = rsqrtf(var + EPS);
  int t = t0 + row;
  mu_a[(size_t)b*TT + t] = mu;
  rs_a[(size_t)b*TT + t] = rs;
  const float4* gsm = (const float4*)(gsum + b*NH);
  const float4* csm = (const float4*)(cst + b*NH);
#pragma unroll
  for (int hq=0; hq<4; hq++){
    float4 gq = gsm[hq], cq = csm[hq];
    float g4[4] = {gq.x, gq.y, gq.z, gq.w};
    float c4[4] = {cq.x, cq.y, cq.z, cq.w};
#pragma unroll
    for (int k=0;k<4;k++){
      int h = hq*4+k;
      float sc = (rs*(acc[h] - mu*g4[k]) + c4[k]) * 0.125f;
      scores[((size_t)b*NH + h)*TT + t] = sc;
    }
  }
}

// ------------- K2: masked softmax + alpha/beta -------------
// grid (NH, B), 256 threads
__global__ __launch_bounds__(256) void k_softmax(const float* __restrict__ scores,
   const float* __restrict__ mu_a, const float* __restrict__ rs_a,
   const int* __restrict__ valid, float* __restrict__ alpha_t, float* __restrict__ beta)
{
  int h = blockIdx.x, b = blockIdx.y;
  int n = valid[b];
  int tid = threadIdx.x;
  __shared__ float e_l[TT];
  __shared__ float red[64];
  const float* sc = scores + ((size_t)b*NH + h)*TT;
  float lmax = -1e30f;
  for (int t=tid; t<n; t+=256){ float v = sc[t]; e_l[t]=v; lmax = fmaxf(lmax, v); }
  float m = bredMax(lmax, red);
  float ls = 0.f, lb = 0.f;
  for (int t=tid; t<n; t+=256){
    float e = expf(e_l[t] - m);
    e_l[t] = e;
    ls += e;
    lb = fmaf(e, rs_a[(size_t)b*TT+t]*mu_a[(size_t)b*TT+t], lb);
  }
  float S  = bredSum(ls, red);
  float Bs = bredSum(lb, red);
  float inv = 1.f/S;
  for (int t=tid; t<n; t+=256)
    alpha_t[((size_t)b*TT + t)*NH + h] = e_l[t]*rs_a[(size_t)b*TT+t]*inv;
  if (tid == 0) beta[b*NH+h] = Bs*inv;
}

// ------------- K3: partial u accumulation -------------
// grid (NC, B), 512 threads; lane owns 2 d's
__global__ __launch_bounds__(512) void k_accum(
    const float* __restrict__ X, const float* __restrict__ alpha_t,
    const int* __restrict__ valid, float* __restrict__ part)
{
  int c = blockIdx.x, b = blockIdx.y;
  int tid = threadIdx.x;
  int t0 = c*CT;
  int tend = min(valid[b], t0 + CT);
  float ax[16], ay[16];
#pragma unroll
  for (int h=0;h<16;h++){ ax[h]=0.f; ay[h]=0.f; }
  const float2* xb = (const float2*)(X + (size_t)b*TT*DD);
#pragma unroll 2
  for (int t=t0; t<tend; t++){
    float2 xv = xb[(size_t)t*(DD/2) + tid];
    const float4* ap = (const float4*)(alpha_t + ((size_t)b*TT + t)*NH);
    float4 a0 = ap[0], a1 = ap[1], a2 = ap[2], a3 = ap[3];
    float a[16] = {a0.x,a0.y,a0.z,a0.w, a1.x,a1.y,a1.z,a1.w,
                   a2.x,a2.y,a2.z,a2.w, a3.x,a3.y,a3.z,a3.w};
#pragma unroll
    for (int h=0;h<16;h++){
      ax[h] = fmaf(a[h], xv.x, ax[h]);
      ay[h] = fmaf(a[h], xv.y, ay[h]);
    }
  }
  float* pp = part + (((size_t)c*BB + b)*NH)*DD;
#pragma unroll
  for (int h=0;h<16;h++)
    *(float2*)(pp + (size_t)h*DD + tid*2) = make_float2(ax[h], ay[h]);
}

// ------------- K4: reduce partials + finalize u -------------
// grid (NH, B), 256 threads
__global__ __launch_bounds__(256) void k_ufin(const float* __restrict__ part,
   const float* __restrict__ beta, const float* __restrict__ g_kv,
   const float* __restrict__ b_kv, float* __restrict__ u)
{
  int h = blockIdx.x, b = blockIdx.y;
  int tid = threadIdx.x;
  int d = tid*4;
  float4 s = make_float4(0.f,0.f,0.f,0.f);
#pragma unroll
  for (int c=0;c<NC;c++){
    float4 v = *(const float4*)(part + (((size_t)c*BB + b)*NH + h)*DD + d);
    s.x+=v.x; s.y+=v.y; s.z+=v.z; s.w+=v.w;
  }
  float be = beta[b*NH+h];
  float4 g = *(const float4*)(g_kv + d);
  float4 bv = *(const float4*)(b_kv + d);
  float4 r;
  r.x = fmaf(g.x, s.x-be, bv.x);
  r.y = fmaf(g.y, s.y-be, bv.y);
  r.z = fmaf(g.z, s.z-be, bv.z);
  r.w = fmaf(g.w, s.w-be, bv.w);
  *(float4*)(u + ((size_t)b*NH + h)*DD + d) = r;
}

// ------------- K5a: ctx = Wv_h @ u + bv -------------
// grid (NH, B), 256 threads
__global__ __launch_bounds__(256) void k_ctx(const float* __restrict__ u,
    const float* __restrict__ Wfull, const float* __restrict__ bfull,
    float* __restrict__ ctx)
{
  int h = blockIdx.x, b = blockIdx.y;
  int tid = threadIdx.x;
  __shared__ float ul[DD];
  __shared__ float Wl[64][65];
  __shared__ float red2[4][64];
  ((float4*)ul)[tid] = ((const float4*)(u + ((size_t)b*NH + h)*DD))[tid];
  int j = tid & 63, quart = tid >> 6;
  float acc = 0.f;
  const float* Wv = Wfull + (size_t)2*DD*DD;
  for (int dc=0; dc<DD; dc+=64){
#pragma unroll
    for (int p=0;p<4;p++){
      int fi = p*256 + tid, r = fi >> 4, q4 = fi & 15;
      float4 v = *(const float4*)(Wv + (size_t)(h*HDIM + r)*DD + dc + q4*4);
      Wl[r][q4*4+0]=v.x; Wl[r][q4*4+1]=v.y; Wl[r][q4*4+2]=v.z; Wl[r][q4*4+3]=v.w;
    }
    __syncthreads();
#pragma unroll
    for (int i=0;i<16;i++)
      acc = fmaf(Wl[j][quart*16+i], ul[dc + quart*16 + i], acc);
    __syncthreads();
  }
  red2[quart][j] = acc;
  __syncthreads();
  if (quart == 0){
    float v = red2[0][j] + red2[1][j] + red2[2][j] + red2[3][j];
    ctx[(size_t)b*DD + h*HDIM + j] = v + bfull[2*DD + h*HDIM + j];
  }
}

// ------------- K5c: out = LN(o + h_t) -------------
__global__ __launch_bounds__(256) void k_outln(const float* __restrict__ o,
   const float* __restrict__ h_t, const float* __restrict__ g,
   const float* __restrict__ bb, float* __restrict__ out)
{
  int b = blockIdx.x, tid = threadIdx.x;
  __shared__ float red[64];
  float4 a = ((const float4*)(o + (size_t)b*DD))[tid];
  float4 r = ((const float4*)(h_t + (size_t)b*DD))[tid];
  a.x+=r.x; a.y+=r.y; a.z+=r.z; a.w+=r.w;
  float s = a.x + a.y + a.z + a.w;
  s = bredSum(s, red);
  float mu = s * (1.f/DD);
  float d0=a.x-mu, d1=a.y-mu, d2=a.z-mu, d3=a.w-mu;
  float s2 = d0*d0 + d1*d1 + d2*d2 + d3*d3;
  s2 = bredSum(s2, red);
  float rs = rsqrtf(s2*(1.f/DD) + EPS);
  float4 gv = ((const float4*)g)[tid], bv = ((const float4*)bb)[tid];
  float4 ov;
  ov.x = fmaf(d0*rs, gv.x, bv.x);
  ov.y = fmaf(d1*rs, gv.y, bv.y);
  ov.z = fmaf(d2*rs, gv.z, bv.z);
  ov.w = fmaf(d3*rs, gv.w, bv.w);
  ((float4*)(out + (size_t)b*DD))[tid] = ov;
}

extern "C" void kernel_launch(void* const* d_in, const int* in_sizes, int n_in,
                              void* d_out, int out_size, void* d_ws, size_t ws_size,
                              hipStream_t stream) {
  const float* h_t     = (const float*)d_in[0];
  const float* H_p     = (const float*)d_in[1];
  const int*   valid   = (const int*)  d_in[2];
  const float* ln_q_g  = (const float*)d_in[3];
  const float* ln_q_b  = (const float*)d_in[4];
  const float* ln_kv_g = (const float*)d_in[5];
  const float* ln_kv_b = (const float*)d_in[6];
  const float* ln_out_g= (const float*)d_in[7];
  const float* ln_out_b= (const float*)d_in[8];
  const float* log_tau = (const float*)d_in[9];
  const float* in_w    = (const float*)d_in[10];
  const float* in_b    = (const float*)d_in[11];
  const float* out_w   = (const float*)d_in[12];
  const float* out_b   = (const float*)d_in[13];
  float* out = (float*)d_out;

  float* ws     = (float*)d_ws;
  float* q      = ws;
  float* qh     = q      + BB*DD;
  float* gs_t   = qh     + BB*DD;
  float* gsum   = gs_t   + (size_t)BB*DD*NH;
  float* cst    = gsum   + BB*NH;
  float* scores = cst    + BB*NH;
  float* mu_a   = scores + (size_t)BB*NH*TT;
  float* rs_a   = mu_a   + BB*TT;
  float* alpha  = rs_a   + BB*TT;
  float* beta   = alpha  + (size_t)BB*TT*NH;
  float* u      = beta   + BB*NH;
  float* ctx    = u      + (size_t)BB*NH*DD;
  float* o      = ctx    + BB*DD;
  float* part   = o      + BB*DD;   // NC*B*NH*D floats; also reused as gemm partials

  k_qln<<<BB, 256, 0, stream>>>(h_t, ln_q_g, ln_q_b, log_tau, q);
  k_gemmsplit<<<dim3(16,8), 256, 0, stream>>>(q, in_w, part);
  k_gemmred<<<BB, 256, 0, stream>>>(part, in_b, qh);
  k_prep_s<<<dim3(NH,BB), 256, 0, stream>>>(qh, in_w, in_b, ln_kv_g, ln_kv_b, gs_t, gsum, cst);
  k_scores<<<dim3(TT/128,BB), 128, 0, stream>>>(H_p, valid, gs_t, gsum, cst, scores, mu_a, rs_a);
  k_softmax<<<dim3(NH,BB), 256, 0, stream>>>(scores, mu_a, rs_a, valid, alpha, beta);
  k_accum<<<dim3(NC,BB), 512, 0, stream>>>(H_p, alpha, valid, part);
  k_ufin<<<dim3(NH,BB), 256, 0, stream>>>(part, beta, ln_kv_g, ln_kv_b, u);
  k_ctx<<<dim3(NH,BB), 256, 0, stream>>>(u, in_w, in_b, ctx);
  k_gemmsplit<<<dim3(16,8), 256, 0, stream>>>(ctx, out_w, part);
  k_gemmred<<<BB, 256, 0, stream>>>(part, out_b, o);
  k_outln<<<BB, 256, 0, stream>>>(o, h_t, ln_out_g, ln_out_b, out);
}

// Round 2
// 301.543 us; speedup vs baseline: 1.0607x; 1.0607x over previous
//
#include <hip/hip_runtime.h>
#include <math.h>

#define BB 32
#define TT 2048
#define DD 1024
#define NH 16
#define HDIM 64
#define EPS 1e-5f

// ---------------- reduction helpers ----------------
__device__ __forceinline__ float wredSum(float v){
  v += __shfl_down(v, 32, 64);
  v += __shfl_down(v, 16, 64);
  v += __shfl_down(v, 8, 64);
  v += __shfl_down(v, 4, 64);
  v += __shfl_down(v, 2, 64);
  v += __shfl_down(v, 1, 64);
  return v;
}
__device__ __forceinline__ float wredMax(float v){
  v = fmaxf(v, __shfl_down(v, 32, 64));
  v = fmaxf(v, __shfl_down(v, 16, 64));
  v = fmaxf(v, __shfl_down(v, 8, 64));
  v = fmaxf(v, __shfl_down(v, 4, 64));
  v = fmaxf(v, __shfl_down(v, 2, 64));
  v = fmaxf(v, __shfl_down(v, 1, 64));
  return v;
}
__device__ float bredSum(float v, float* red){
  int lane = threadIdx.x & 63, w = threadIdx.x >> 6, nw = blockDim.x >> 6;
  v = wredSum(v);
  __syncthreads();
  if (lane == 0) red[w] = v;
  __syncthreads();
  if (w == 0){
    float x = (lane < nw) ? red[lane] : 0.f;
    x = wredSum(x);
    if (lane == 0) red[0] = x;
  }
  __syncthreads();
  return red[0];
}
__device__ float bredMax(float v, float* red){
  int lane = threadIdx.x & 63, w = threadIdx.x >> 6, nw = blockDim.x >> 6;
  v = wredMax(v);
  __syncthreads();
  if (lane == 0) red[w] = v;
  __syncthreads();
  if (w == 0){
    float x = (lane < nw) ? red[lane] : -1e30f;
    x = wredMax(x);
    if (lane == 0) red[0] = x;
  }
  __syncthreads();
  return red[0];
}

// ---------------- K0a: q = LN(h_t)*tau ----------------
__global__ __launch_bounds__(256) void k_qln(const float* __restrict__ h_t,
   const float* __restrict__ g, const float* __restrict__ bb,
   const float* __restrict__ log_tau, float* __restrict__ q)
{
  int b = blockIdx.x, tid = threadIdx.x;
  __shared__ float red[64];
  float4 x = ((const float4*)(h_t + (size_t)b*DD))[tid];
  float s = x.x + x.y + x.z + x.w;
  s = bredSum(s, red);
  float mu = s * (1.f/DD);
  float d0=x.x-mu, d1=x.y-mu, d2=x.z-mu, d3=x.w-mu;
  float s2 = d0*d0 + d1*d1 + d2*d2 + d3*d3;
  s2 = bredSum(s2, red);
  float rs = rsqrtf(s2*(1.f/DD) + EPS);
  float tau = fminf(fmaxf(expf(log_tau[0]), 0.25f), 4.0f);
  float4 gv = ((const float4*)g)[tid], bv = ((const float4*)bb)[tid];
  float4 o;
  o.x = (d0*rs*gv.x + bv.x)*tau;
  o.y = (d1*rs*gv.y + bv.y)*tau;
  o.z = (d2*rs*gv.z + bv.z)*tau;
  o.w = (d3*rs*gv.w + bv.w)*tau;
  ((float4*)(q + (size_t)b*DD))[tid] = o;
}

// ------------- small GEMM (32x1024 @ 1024x1024^T), d-split partials -------------
__global__ __launch_bounds__(256) void k_gemmsplit(const float* __restrict__ A,
    const float* __restrict__ W, float* __restrict__ p2)
{
  int ec = blockIdx.x, ds = blockIdx.y;
  int tid = threadIdx.x;
  __shared__ float Wl[64][132];
  __shared__ float Al[32][132];
  int d0 = ds*128, e0 = ec*64;
#pragma unroll
  for (int p=0;p<8;p++){
    int fi = p*256 + tid, r = fi >> 5, q4 = fi & 31;
    float4 v = *(const float4*)(W + (size_t)(e0+r)*DD + d0 + q4*4);
    *(float4*)&Wl[r][q4*4] = v;
  }
#pragma unroll
  for (int p=0;p<4;p++){
    int fi = p*256 + tid, r = fi >> 5, q4 = fi & 31;
    float4 v = *(const float4*)(A + (size_t)r*DD + d0 + q4*4);
    *(float4*)&Al[r][q4*4] = v;
  }
  __syncthreads();
  int eL = tid & 63, bg = tid >> 6;
  float acc[8];
#pragma unroll
  for (int i=0;i<8;i++) acc[i]=0.f;
  for (int d4=0; d4<32; d4++){
    float4 w = *(float4*)&Wl[eL][d4*4];
#pragma unroll
    for (int i=0;i<8;i++){
      float4 a = *(float4*)&Al[bg*8+i][d4*4];
      acc[i] = fmaf(w.x, a.x, acc[i]);
      acc[i] = fmaf(w.y, a.y, acc[i]);
      acc[i] = fmaf(w.z, a.z, acc[i]);
      acc[i] = fmaf(w.w, a.w, acc[i]);
    }
  }
#pragma unroll
  for (int i=0;i<8;i++)
    p2[((size_t)ds*BB + (bg*8+i))*DD + e0 + eL] = acc[i];
}

__global__ __launch_bounds__(256) void k_gemmred(const float* __restrict__ p2,
    const float* __restrict__ bias, float* __restrict__ out)
{
  int b = blockIdx.x, tid = threadIdx.x;
  int e = tid*4;
  float4 s = make_float4(0.f,0.f,0.f,0.f);
#pragma unroll
  for (int ds=0; ds<8; ds++){
    float4 v = *(const float4*)(p2 + ((size_t)ds*BB + b)*DD + e);
    s.x+=v.x; s.y+=v.y; s.z+=v.z; s.w+=v.w;
  }
  float4 bv = *(const float4*)(bias + e);
  s.x+=bv.x; s.y+=bv.y; s.z+=bv.z; s.w+=bv.w;
  *(float4*)(out + (size_t)b*DD + e) = s;
}

// ------------- K0c: s = Wk_h^T qh_h ; gs_t, gsum, cst -------------
__global__ __launch_bounds__(256) void k_prep_s(const float* __restrict__ qh,
    const float* __restrict__ Wfull, const float* __restrict__ bfull,
    const float* __restrict__ g_kv, const float* __restrict__ b_kv,
    float* __restrict__ gs_t, float* __restrict__ gsum, float* __restrict__ cst)
{
  int h = blockIdx.x, b = blockIdx.y;
  int tid = threadIdx.x;
  __shared__ float qhl[64];
  __shared__ float red[64];
  if (tid < 64) qhl[tid] = qh[(size_t)b*DD + h*HDIM + tid];
  __syncthreads();
  float lgs = 0.f, lbs = 0.f;
  const float* Wk = Wfull + (size_t)DD*DD;
#pragma unroll 1
  for (int d = tid; d < DD; d += 256){
    float s = 0.f;
#pragma unroll 8
    for (int j=0;j<64;j++)
      s = fmaf(Wk[(size_t)(h*HDIM+j)*DD + d], qhl[j], s);
    float gsv = s * g_kv[d];
    gs_t[((size_t)b*DD + d)*NH + h] = gsv;
    lgs += gsv;
    lbs = fmaf(s, b_kv[d], lbs);
  }
  float lc = 0.f;
  if (tid < 64) lc = qhl[tid] * bfull[DD + h*HDIM + tid];
  float tg = bredSum(lgs, red);
  float tb = bredSum(lbs + lc, red);
  if (tid == 0){ gsum[b*NH+h] = tg; cst[b*NH+h] = tb; }
}

// ------------- K1: fused row-stats + scores (rebuilt) -------------
// 64 t-rows/block, 256 threads (4 waves). thread = (row, head-quad).
// Each thread sees ALL d for its row -> private stats, no combine.
// X staged through double-buffered XOR-swizzled LDS chunks of 64 d.
#define SR 64
#define SDC 64
__global__ __launch_bounds__(256) void k_scores(
    const float* __restrict__ X, const int* __restrict__ valid,
    const float* __restrict__ gs_t, const float* __restrict__ gsum,
    const float* __restrict__ cst, float* __restrict__ scores,
    float* __restrict__ mu_a, float* __restrict__ rs_a)
{
  int tc = blockIdx.x, b = blockIdx.y;
  int t0 = tc * SR;
  if (t0 >= valid[b]) return;
  int tid = threadIdx.x;
  int row = tid & 63, hq = tid >> 6, rx = row & 7;
  __shared__ float4 tile[2][SR*16];   // 16B units, u = cg ^ (r&7) swizzle
  const float* xb = X + ((size_t)b*TT + t0)*DD;
  float4 ld0, ld1, ld2, ld3;
  float a0=0.f, a1=0.f, a2=0.f, a3=0.f, ssum=0.f, ssq=0.f;

  // addressing for cooperative staging: fi = p*256+tid -> r=fi>>4, cg=fi&15
  int r0 = tid >> 4, cg0 = tid & 15;              // p=0
  // p adds 256 to fi: r += 16, cg same
#define LOADC(c) { const float* pb = xb + (size_t)(c)*SDC; \
    ld0 = *(const float4*)(pb + (size_t)(r0+ 0)*DD + cg0*4); \
    ld1 = *(const float4*)(pb + (size_t)(r0+16)*DD + cg0*4); \
    ld2 = *(const float4*)(pb + (size_t)(r0+32)*DD + cg0*4); \
    ld3 = *(const float4*)(pb + (size_t)(r0+48)*DD + cg0*4); }
#define STOREC(c) { float4* tb = tile[(c)&1]; int u = cg0; \
    tb[(r0+ 0)*16 + (u ^ ((r0+ 0)&7))] = ld0; \
    tb[(r0+16)*16 + (u ^ ((r0+16)&7))] = ld1; \
    tb[(r0+32)*16 + (u ^ ((r0+32)&7))] = ld2; \
    tb[(r0+48)*16 + (u ^ ((r0+48)&7))] = ld3; }

  LOADC(0);
  STOREC(0);
  for (int c = 0; c < DD/SDC; ++c){
    if (c+1 < DD/SDC) LOADC(c+1);
    __syncthreads();
    {
      const float4* tb = tile[c&1] + row*16;
      const float* gsp = gs_t + ((size_t)b*DD + c*SDC)*NH + hq*4;
#pragma unroll
      for (int d4=0; d4<16; d4++){
        float4 xv = tb[d4 ^ rx];
        float4 g0 = *(const float4*)(gsp + (d4*4+0)*NH);
        float4 g1 = *(const float4*)(gsp + (d4*4+1)*NH);
        float4 g2 = *(const float4*)(gsp + (d4*4+2)*NH);
        float4 g3 = *(const float4*)(gsp + (d4*4+3)*NH);
        ssum += xv.x + xv.y + xv.z + xv.w;
        ssq = fmaf(xv.x,xv.x,ssq); ssq = fmaf(xv.y,xv.y,ssq);
        ssq = fmaf(xv.z,xv.z,ssq); ssq = fmaf(xv.w,xv.w,ssq);
        a0 = fmaf(xv.x,g0.x,a0); a1 = fmaf(xv.x,g0.y,a1);
        a2 = fmaf(xv.x,g0.z,a2); a3 = fmaf(xv.x,g0.w,a3);
        a0 = fmaf(xv.y,g1.x,a0); a1 = fmaf(xv.y,g1.y,a1);
        a2 = fmaf(xv.y,g1.z,a2); a3 = fmaf(xv.y,g1.w,a3);
        a0 = fmaf(xv.z,g2.x,a0); a1 = fmaf(xv.z,g2.y,a1);
        a2 = fmaf(xv.z,g2.z,a2); a3 = fmaf(xv.z,g2.w,a3);
        a0 = fmaf(xv.w,g3.x,a0); a1 = fmaf(xv.w,g3.y,a1);
        a2 = fmaf(xv.w,g3.z,a2); a3 = fmaf(xv.w,g3.w,a3);
      }
    }
    if (c+1 < DD/SDC){
      __syncthreads();
      STOREC(c+1);
    }
  }
#undef LOADC
#undef STOREC
  float mu = ssum * (1.f/DD);
  float var = ssq*(1.f/DD) - mu*mu;
  float rs = rsqrtf(var + EPS);
  int t = t0 + row;
  if (hq == 0){
    mu_a[(size_t)b*TT + t] = mu;
    rs_a[(size_t)b*TT + t] = rs;
  }
  float4 gq = *(const float4*)(gsum + b*NH + hq*4);
  float4 cq = *(const float4*)(cst  + b*NH + hq*4);
  float* sp = scores + ((size_t)b*NH + hq*4)*TT + t;
  sp[0*TT] = (rs*(a0 - mu*gq.x) + cq.x)*0.125f;
  sp[1*TT] = (rs*(a1 - mu*gq.y) + cq.y)*0.125f;
  sp[2*TT] = (rs*(a2 - mu*gq.z) + cq.z)*0.125f;
  sp[3*TT] = (rs*(a3 - mu*gq.w) + cq.w)*0.125f;
}

// ------------- K2: masked softmax + alpha/beta -------------
__global__ __launch_bounds__(256) void k_softmax(const float* __restrict__ scores,
   const float* __restrict__ mu_a, const float* __restrict__ rs_a,
   const int* __restrict__ valid, float* __restrict__ alpha_t, float* __restrict__ beta)
{
  int h = blockIdx.x, b = blockIdx.y;
  int n = valid[b];
  int tid = threadIdx.x;
  __shared__ float e_l[TT];
  __shared__ float red[64];
  const float* sc = scores + ((size_t)b*NH + h)*TT;
  float lmax = -1e30f;
  for (int t=tid; t<n; t+=256){ float v = sc[t]; e_l[t]=v; lmax = fmaxf(lmax, v); }
  float m = bredMax(lmax, red);
  float ls = 0.f, lb = 0.f;
  for (int t=tid; t<n; t+=256){
    float e = expf(e_l[t] - m);
    e_l[t] = e;
    ls += e;
    lb = fmaf(e, rs_a[(size_t)b*TT+t]*mu_a[(size_t)b*TT+t], lb);
  }
  float S  = bredSum(ls, red);
  float Bs = bredSum(lb, red);
  float inv = 1.f/S;
  for (int t=tid; t<n; t+=256)
    alpha_t[((size_t)b*TT + t)*NH + h] = e_l[t]*rs_a[(size_t)b*TT+t]*inv;
  if (tid == 0) beta[b*NH+h] = Bs*inv;
}

// ------------- K3: partial u accumulation (nc runtime) -------------
__global__ __launch_bounds__(512) void k_accum(
    const float* __restrict__ X, const float* __restrict__ alpha_t,
    const int* __restrict__ valid, float* __restrict__ part, int ct)
{
  int c = blockIdx.x, b = blockIdx.y;
  int tid = threadIdx.x;
  int t0 = c*ct;
  int tend = min(valid[b], t0 + ct);
  float ax[16], ay[16];
#pragma unroll
  for (int h=0;h<16;h++){ ax[h]=0.f; ay[h]=0.f; }
  const float2* xb = (const float2*)(X + (size_t)b*TT*DD);
#pragma unroll 2
  for (int t=t0; t<tend; t++){
    float2 xv = xb[(size_t)t*(DD/2) + tid];
    const float4* ap = (const float4*)(alpha_t + ((size_t)b*TT + t)*NH);
    float4 q0 = ap[0], q1 = ap[1], q2 = ap[2], q3 = ap[3];
    float a[16] = {q0.x,q0.y,q0.z,q0.w, q1.x,q1.y,q1.z,q1.w,
                   q2.x,q2.y,q2.z,q2.w, q3.x,q3.y,q3.z,q3.w};
#pragma unroll
    for (int h=0;h<16;h++){
      ax[h] = fmaf(a[h], xv.x, ax[h]);
      ay[h] = fmaf(a[h], xv.y, ay[h]);
    }
  }
  float* pp = part + (((size_t)c*BB + b)*NH)*DD;
#pragma unroll
  for (int h=0;h<16;h++)
    *(float2*)(pp + (size_t)h*DD + tid*2) = make_float2(ax[h], ay[h]);
}

// ------------- K4: reduce partials + finalize u -------------
__global__ __launch_bounds__(256) void k_ufin(const float* __restrict__ part,
   const float* __restrict__ beta, const float* __restrict__ g_kv,
   const float* __restrict__ b_kv, float* __restrict__ u, int nc)
{
  int h = blockIdx.x, b = blockIdx.y;
  int tid = threadIdx.x;
  int d = tid*4;
  float4 s = make_float4(0.f,0.f,0.f,0.f);
  for (int c=0;c<nc;c++){
    float4 v = *(const float4*)(part + (((size_t)c*BB + b)*NH + h)*DD + d);
    s.x+=v.x; s.y+=v.y; s.z+=v.z; s.w+=v.w;
  }
  float be = beta[b*NH+h];
  float4 g = *(const float4*)(g_kv + d);
  float4 bv = *(const float4*)(b_kv + d);
  float4 r;
  r.x = fmaf(g.x, s.x-be, bv.x);
  r.y = fmaf(g.y, s.y-be, bv.y);
  r.z = fmaf(g.z, s.z-be, bv.z);
  r.w = fmaf(g.w, s.w-be, bv.w);
  *(float4*)(u + ((size_t)b*NH + h)*DD + d) = r;
}

// ------------- K5a: ctx = Wv_h @ u + bv -------------
__global__ __launch_bounds__(256) void k_ctx(const float* __restrict__ u,
    const float* __restrict__ Wfull, const float* __restrict__ bfull,
    float* __restrict__ ctx)
{
  int h = blockIdx.x, b = blockIdx.y;
  int tid = threadIdx.x;
  __shared__ float ul[DD];
  __shared__ float Wl[64][65];
  __shared__ float red2[4][64];
  ((float4*)ul)[tid] = ((const float4*)(u + ((size_t)b*NH + h)*DD))[tid];
  int j = tid & 63, quart = tid >> 6;
  float acc = 0.f;
  const float* Wv = Wfull + (size_t)2*DD*DD;
  for (int dc=0; dc<DD; dc+=64){
#pragma unroll
    for (int p=0;p<4;p++){
      int fi = p*256 + tid, r = fi >> 4, q4 = fi & 15;
      float4 v = *(const float4*)(Wv + (size_t)(h*HDIM + r)*DD + dc + q4*4);
      Wl[r][q4*4+0]=v.x; Wl[r][q4*4+1]=v.y; Wl[r][q4*4+2]=v.z; Wl[r][q4*4+3]=v.w;
    }
    __syncthreads();
#pragma unroll
    for (int i=0;i<16;i++)
      acc = fmaf(Wl[j][quart*16+i], ul[dc + quart*16 + i], acc);
    __syncthreads();
  }
  red2[quart][j] = acc;
  __syncthreads();
  if (quart == 0){
    float v = red2[0][j] + red2[1][j] + red2[2][j] + red2[3][j];
    ctx[(size_t)b*DD + h*HDIM + j] = v + bfull[2*DD + h*HDIM + j];
  }
}

// ------------- K5c: out = LN(o + h_t) -------------
__global__ __launch_bounds__(256) void k_outln(const float* __restrict__ o,
   const float* __restrict__ h_t, const float* __restrict__ g,
   const float* __restrict__ bb, float* __restrict__ out)
{
  int b = blockIdx.x, tid = threadIdx.x;
  __shared__ float red[64];
  float4 a = ((const float4*)(o + (size_t)b*DD))[tid];
  float4 r = ((const float4*)(h_t + (size_t)b*DD))[tid];
  a.x+=r.x; a.y+=r.y; a.z+=r.z; a.w+=r.w;
  float s = a.x + a.y + a.z + a.w;
  s = bredSum(s, red);
  float mu = s * (1.f/DD);
  float d0=a.x-mu, d1=a.y-mu, d2=a.z-mu, d3=a.w-mu;
  float s2 = d0*d0 + d1*d1 + d2*d2 + d3*d3;
  s2 = bredSum(s2, red);
  float rs = rsqrtf(s2*(1.f/DD) + EPS);
  float4 gv = ((const float4*)g)[tid], bv = ((const float4*)bb)[tid];
  float4 ov;
  ov.x = fmaf(d0*rs, gv.x, bv.x);
  ov.y = fmaf(d1*rs, gv.y, bv.y);
  ov.z = fmaf(d2*rs, gv.z, bv.z);
  ov.w = fmaf(d3*rs, gv.w, bv.w);
  ((float4*)(out + (size_t)b*DD))[tid] = ov;
}

extern "C" void kernel_launch(void* const* d_in, const int* in_sizes, int n_in,
                              void* d_out, int out_size, void* d_ws, size_t ws_size,
                              hipStream_t stream) {
  const float* h_t     = (const float*)d_in[0];
  const float* H_p     = (const float*)d_in[1];
  const int*   valid   = (const int*)  d_in[2];
  const float* ln_q_g  = (const float*)d_in[3];
  const float* ln_q_b  = (const float*)d_in[4];
  const float* ln_kv_g = (const float*)d_in[5];
  const float* ln_kv_b = (const float*)d_in[6];
  const float* ln_out_g= (const float*)d_in[7];
  const float* ln_out_b= (const float*)d_in[8];
  const float* log_tau = (const float*)d_in[9];
  const float* in_w    = (const float*)d_in[10];
  const float* in_b    = (const float*)d_in[11];
  const float* out_w   = (const float*)d_in[12];
  const float* out_b   = (const float*)d_in[13];
  float* out = (float*)d_out;

  float* ws     = (float*)d_ws;
  float* q      = ws;
  float* qh     = q      + BB*DD;
  float* gs_t   = qh     + BB*DD;
  float* gsum   = gs_t   + (size_t)BB*DD*NH;
  float* cst    = gsum   + BB*NH;
  float* scores = cst    + BB*NH;
  float* mu_a   = scores + (size_t)BB*NH*TT;
  float* rs_a   = mu_a   + BB*TT;
  float* alpha  = rs_a   + BB*TT;
  float* beta   = alpha  + (size_t)BB*TT*NH;
  float* u      = beta   + BB*NH;
  float* ctx    = u      + (size_t)BB*NH*DD;
  float* o      = ctx    + BB*DD;
  float* part   = o      + BB*DD;   // nc*B*NH*D floats; also reused as gemm partials

  // pick nc (t-chunks for k_accum) based on available workspace
  size_t base_floats = (size_t)(part - ws);
  int nc = 16;
  if ((base_floats + (size_t)nc*BB*NH*DD) * sizeof(float) > ws_size) nc = 8;
  int ct = TT / nc;

  k_qln<<<BB, 256, 0, stream>>>(h_t, ln_q_g, ln_q_b, log_tau, q);
  k_gemmsplit<<<dim3(16,8), 256, 0, stream>>>(q, in_w, part);
  k_gemmred<<<BB, 256, 0, stream>>>(part, in_b, qh);
  k_prep_s<<<dim3(NH,BB), 256, 0, stream>>>(qh, in_w, in_b, ln_kv_g, ln_kv_b, gs_t, gsum, cst);
  k_scores<<<dim3(TT/SR,BB), 256, 0, stream>>>(H_p, valid, gs_t, gsum, cst, scores, mu_a, rs_a);
  k_softmax<<<dim3(NH,BB), 256, 0, stream>>>(scores, mu_a, rs_a, valid, alpha, beta);
  k_accum<<<dim3(nc,BB), 512, 0, stream>>>(H_p, alpha, valid, part, ct);
  k_ufin<<<dim3(NH,BB), 256, 0, stream>>>(part, beta, ln_kv_g, ln_kv_b, u, nc);
  k_ctx<<<dim3(NH,BB), 256, 0, stream>>>(u, in_w, in_b, ctx);
  k_gemmsplit<<<dim3(16,8), 256, 0, stream>>>(ctx, out_w, part);
  k_gemmred<<<BB, 256, 0, stream>>>(part, out_b, o);
  k_outln<<<BB, 256, 0, stream>>>(o, h_t, ln_out_g, ln_out_b, out);
}

// Round 3
// 184.087 us; speedup vs baseline: 1.7374x; 1.6380x over previous
//
#include <hip/hip_runtime.h>
#include <math.h>

#define BB 32
#define TT 2048
#define DD 1024
#define NH 16
#define HDIM 64
#define EPS 1e-5f

// ---------------- reduction helpers ----------------
__device__ __forceinline__ float wredSum(float v){
  v += __shfl_down(v, 32, 64);
  v += __shfl_down(v, 16, 64);
  v += __shfl_down(v, 8, 64);
  v += __shfl_down(v, 4, 64);
  v += __shfl_down(v, 2, 64);
  v += __shfl_down(v, 1, 64);
  return v;
}
__device__ __forceinline__ float wredMax(float v){
  v = fmaxf(v, __shfl_down(v, 32, 64));
  v = fmaxf(v, __shfl_down(v, 16, 64));
  v = fmaxf(v, __shfl_down(v, 8, 64));
  v = fmaxf(v, __shfl_down(v, 4, 64));
  v = fmaxf(v, __shfl_down(v, 2, 64));
  v = fmaxf(v, __shfl_down(v, 1, 64));
  return v;
}
__device__ float bredSum(float v, float* red){
  int lane = threadIdx.x & 63, w = threadIdx.x >> 6, nw = blockDim.x >> 6;
  v = wredSum(v);
  __syncthreads();
  if (lane == 0) red[w] = v;
  __syncthreads();
  if (w == 0){
    float x = (lane < nw) ? red[lane] : 0.f;
    x = wredSum(x);
    if (lane == 0) red[0] = x;
  }
  __syncthreads();
  return red[0];
}
__device__ float bredMax(float v, float* red){
  int lane = threadIdx.x & 63, w = threadIdx.x >> 6, nw = blockDim.x >> 6;
  v = wredMax(v);
  __syncthreads();
  if (lane == 0) red[w] = v;
  __syncthreads();
  if (w == 0){
    float x = (lane < nw) ? red[lane] : -1e30f;
    x = wredMax(x);
    if (lane == 0) red[0] = x;
  }
  __syncthreads();
  return red[0];
}

// ---------------- K0a: q = LN(h_t)*tau ----------------
__global__ __launch_bounds__(256) void k_qln(const float* __restrict__ h_t,
   const float* __restrict__ g, const float* __restrict__ bb,
   const float* __restrict__ log_tau, float* __restrict__ q)
{
  int b = blockIdx.x, tid = threadIdx.x;
  __shared__ float red[64];
  float4 x = ((const float4*)(h_t + (size_t)b*DD))[tid];
  float s = x.x + x.y + x.z + x.w;
  s = bredSum(s, red);
  float mu = s * (1.f/DD);
  float d0=x.x-mu, d1=x.y-mu, d2=x.z-mu, d3=x.w-mu;
  float s2 = d0*d0 + d1*d1 + d2*d2 + d3*d3;
  s2 = bredSum(s2, red);
  float rs = rsqrtf(s2*(1.f/DD) + EPS);
  float tau = fminf(fmaxf(expf(log_tau[0]), 0.25f), 4.0f);
  float4 gv = ((const float4*)g)[tid], bv = ((const float4*)bb)[tid];
  float4 o;
  o.x = (d0*rs*gv.x + bv.x)*tau;
  o.y = (d1*rs*gv.y + bv.y)*tau;
  o.z = (d2*rs*gv.z + bv.z)*tau;
  o.w = (d3*rs*gv.w + bv.w)*tau;
  ((float4*)(q + (size_t)b*DD))[tid] = o;
}

// ------------- small GEMM (32x1024 @ 1024x1024^T), d-split partials -------------
__global__ __launch_bounds__(256) void k_gemmsplit(const float* __restrict__ A,
    const float* __restrict__ W, float* __restrict__ p2)
{
  int ec = blockIdx.x, ds = blockIdx.y;
  int tid = threadIdx.x;
  __shared__ float Wl[64][132];
  __shared__ float Al[32][132];
  int d0 = ds*128, e0 = ec*64;
#pragma unroll
  for (int p=0;p<8;p++){
    int fi = p*256 + tid, r = fi >> 5, q4 = fi & 31;
    float4 v = *(const float4*)(W + (size_t)(e0+r)*DD + d0 + q4*4);
    *(float4*)&Wl[r][q4*4] = v;
  }
#pragma unroll
  for (int p=0;p<4;p++){
    int fi = p*256 + tid, r = fi >> 5, q4 = fi & 31;
    float4 v = *(const float4*)(A + (size_t)r*DD + d0 + q4*4);
    *(float4*)&Al[r][q4*4] = v;
  }
  __syncthreads();
  int eL = tid & 63, bg = tid >> 6;
  float acc[8];
#pragma unroll
  for (int i=0;i<8;i++) acc[i]=0.f;
  for (int d4=0; d4<32; d4++){
    float4 w = *(float4*)&Wl[eL][d4*4];
#pragma unroll
    for (int i=0;i<8;i++){
      float4 a = *(float4*)&Al[bg*8+i][d4*4];
      acc[i] = fmaf(w.x, a.x, acc[i]);
      acc[i] = fmaf(w.y, a.y, acc[i]);
      acc[i] = fmaf(w.z, a.z, acc[i]);
      acc[i] = fmaf(w.w, a.w, acc[i]);
    }
  }
#pragma unroll
  for (int i=0;i<8;i++)
    p2[((size_t)ds*BB + (bg*8+i))*DD + e0 + eL] = acc[i];
}

__global__ __launch_bounds__(256) void k_gemmred(const float* __restrict__ p2,
    const float* __restrict__ bias, float* __restrict__ out)
{
  int b = blockIdx.x, tid = threadIdx.x;
  int e = tid*4;
  float4 s = make_float4(0.f,0.f,0.f,0.f);
#pragma unroll
  for (int ds=0; ds<8; ds++){
    float4 v = *(const float4*)(p2 + ((size_t)ds*BB + b)*DD + e);
    s.x+=v.x; s.y+=v.y; s.z+=v.z; s.w+=v.w;
  }
  float4 bv = *(const float4*)(bias + e);
  s.x+=bv.x; s.y+=bv.y; s.z+=bv.z; s.w+=bv.w;
  *(float4*)(out + (size_t)b*DD + e) = s;
}

// ------------- K0c: s = Wk_h^T qh_h ; gs_t, gsum, cst -------------
__global__ __launch_bounds__(256) void k_prep_s(const float* __restrict__ qh,
    const float* __restrict__ Wfull, const float* __restrict__ bfull,
    const float* __restrict__ g_kv, const float* __restrict__ b_kv,
    float* __restrict__ gs_t, float* __restrict__ gsum, float* __restrict__ cst)
{
  int h = blockIdx.x, b = blockIdx.y;
  int tid = threadIdx.x;
  __shared__ float qhl[64];
  __shared__ float red[64];
  if (tid < 64) qhl[tid] = qh[(size_t)b*DD + h*HDIM + tid];
  __syncthreads();
  float lgs = 0.f, lbs = 0.f;
  const float* Wk = Wfull + (size_t)DD*DD;
#pragma unroll 1
  for (int d = tid; d < DD; d += 256){
    float s = 0.f;
#pragma unroll 8
    for (int j=0;j<64;j++)
      s = fmaf(Wk[(size_t)(h*HDIM+j)*DD + d], qhl[j], s);
    float gsv = s * g_kv[d];
    gs_t[((size_t)b*DD + d)*NH + h] = gsv;
    lgs += gsv;
    lbs = fmaf(s, b_kv[d], lbs);
  }
  float lc = 0.f;
  if (tid < 64) lc = qhl[tid] * bfull[DD + h*HDIM + tid];
  float tg = bredSum(lgs, red);
  float tb = bredSum(lbs + lc, red);
  if (tid == 0){ gsum[b*NH+h] = tg; cst[b*NH+h] = tb; }
}

// ------------- K1: d-split partial scores -------------
// block: 64 t-rows x 256 d (one of 4 d-splits); 256 threads = (row, hq).
// X tile and gs chunk staged in double-buffered LDS; inner loop pure LDS+FMA.
#define SR 64
#define SDC 64
#define DSPLIT 4
#define DPS (DD/DSPLIT)
#define NCH (DPS/SDC)
__global__ __launch_bounds__(256) void k_scores(
    const float* __restrict__ X, const int* __restrict__ valid,
    const float* __restrict__ gs_t,
    float4* __restrict__ pacc, float2* __restrict__ pstat)
{
  int bx = blockIdx.x, b = blockIdx.y;
  int tc = bx & (TT/SR - 1), ds = bx >> 5;   // TT/SR == 32
  int t0 = tc * SR;
  if (t0 >= valid[b]) return;
  int tid = threadIdx.x;
  int row = tid & 63, hq = tid >> 6, rx = row & 15;
  __shared__ float4 xt[2][SR*16];    // 16KB x2, swizzled u = cg ^ (r&15)
  __shared__ float4 gt[2][SDC*4];    // 4KB x2: [d][h-quad]
  const float* xb = X + ((size_t)b*TT + t0)*DD + ds*DPS;
  const float4* gsrc = (const float4*)(gs_t + ((size_t)b*DD + ds*DPS)*NH);
  int r0 = tid >> 4, cg0 = tid & 15;
  float4 ld0, ld1, ld2, ld3, gld;
  float a0=0.f, a1=0.f, a2=0.f, a3=0.f, ssum=0.f, ssq=0.f;
#define LOADC(c) { const float* pb = xb + (c)*SDC; \
    ld0 = *(const float4*)(pb + (size_t)(r0+ 0)*DD + cg0*4); \
    ld1 = *(const float4*)(pb + (size_t)(r0+16)*DD + cg0*4); \
    ld2 = *(const float4*)(pb + (size_t)(r0+32)*DD + cg0*4); \
    ld3 = *(const float4*)(pb + (size_t)(r0+48)*DD + cg0*4); \
    gld = gsrc[(c)*256 + tid]; }
#define STOREC(c) { float4* tb = xt[(c)&1]; int u = cg0 ^ r0; \
    tb[(r0+ 0)*16 + u] = ld0; \
    tb[(r0+16)*16 + u] = ld1; \
    tb[(r0+32)*16 + u] = ld2; \
    tb[(r0+48)*16 + u] = ld3; \
    gt[(c)&1][tid] = gld; }

  LOADC(0);
  STOREC(0);
  for (int c = 0; c < NCH; ++c){
    if (c+1 < NCH) LOADC(c+1);
    __syncthreads();
    {
      const float4* tb = xt[c&1] + row*16;
      const float4* gb = gt[c&1];
#pragma unroll
      for (int d4=0; d4<16; d4++){
        float4 xv = tb[d4 ^ rx];
        float4 g0 = gb[d4*16 + 0 + hq];
        float4 g1 = gb[d4*16 + 4 + hq];
        float4 g2 = gb[d4*16 + 8 + hq];
        float4 g3 = gb[d4*16 + 12 + hq];
        ssum += xv.x + xv.y + xv.z + xv.w;
        ssq = fmaf(xv.x,xv.x,ssq); ssq = fmaf(xv.y,xv.y,ssq);
        ssq = fmaf(xv.z,xv.z,ssq); ssq = fmaf(xv.w,xv.w,ssq);
        a0 = fmaf(xv.x,g0.x,a0); a1 = fmaf(xv.x,g0.y,a1);
        a2 = fmaf(xv.x,g0.z,a2); a3 = fmaf(xv.x,g0.w,a3);
        a0 = fmaf(xv.y,g1.x,a0); a1 = fmaf(xv.y,g1.y,a1);
        a2 = fmaf(xv.y,g1.z,a2); a3 = fmaf(xv.y,g1.w,a3);
        a0 = fmaf(xv.z,g2.x,a0); a1 = fmaf(xv.z,g2.y,a1);
        a2 = fmaf(xv.z,g2.z,a2); a3 = fmaf(xv.z,g2.w,a3);
        a0 = fmaf(xv.w,g3.x,a0); a1 = fmaf(xv.w,g3.y,a1);
        a2 = fmaf(xv.w,g3.z,a2); a3 = fmaf(xv.w,g3.w,a3);
      }
    }
    if (c+1 < NCH){
      __syncthreads();
      STOREC(c+1);
    }
  }
#undef LOADC
#undef STOREC
  int t = t0 + row;
  pacc[((size_t)(ds*BB + b)*4 + hq)*TT + t] = make_float4(a0,a1,a2,a3);
  if (hq == 0) pstat[((size_t)ds*BB + b)*TT + t] = make_float2(ssum, ssq);
}

// ------------- K1b: reduce d-splits -> mu/rs + scores -------------
__global__ __launch_bounds__(256) void k_sred(
    const float4* __restrict__ pacc, const float2* __restrict__ pstat,
    const int* __restrict__ valid,
    const float* __restrict__ gsum, const float* __restrict__ cst,
    float* __restrict__ scores, float* __restrict__ mu_a, float* __restrict__ rs_a)
{
  int tc = blockIdx.x, b = blockIdx.y;
  int t0 = tc * 64;
  if (t0 >= valid[b]) return;
  int tid = threadIdx.x, tl = tid & 63, hq = tid >> 6;
  int t = t0 + tl;
  float4 s = make_float4(0.f,0.f,0.f,0.f);
  float ss = 0.f, sq = 0.f;
#pragma unroll
  for (int ds=0; ds<DSPLIT; ds++){
    float4 v = pacc[((size_t)(ds*BB + b)*4 + hq)*TT + t];
    s.x+=v.x; s.y+=v.y; s.z+=v.z; s.w+=v.w;
    float2 st = pstat[((size_t)ds*BB + b)*TT + t];
    ss += st.x; sq += st.y;
  }
  float mu = ss*(1.f/DD);
  float rs = rsqrtf(sq*(1.f/DD) - mu*mu + EPS);
  if (hq == 0){ mu_a[(size_t)b*TT+t] = mu; rs_a[(size_t)b*TT+t] = rs; }
  float4 gq = *(const float4*)(gsum + b*NH + hq*4);
  float4 cq = *(const float4*)(cst + b*NH + hq*4);
  float* sp = scores + ((size_t)b*NH + hq*4)*TT + t;
  sp[0]    = (rs*(s.x - mu*gq.x) + cq.x)*0.125f;
  sp[TT]   = (rs*(s.y - mu*gq.y) + cq.y)*0.125f;
  sp[2*TT] = (rs*(s.z - mu*gq.z) + cq.z)*0.125f;
  sp[3*TT] = (rs*(s.w - mu*gq.w) + cq.w)*0.125f;
}

// ------------- K2: masked softmax + alpha/beta -------------
__global__ __launch_bounds__(256) void k_softmax(const float* __restrict__ scores,
   const float* __restrict__ mu_a, const float* __restrict__ rs_a,
   const int* __restrict__ valid, float* __restrict__ alpha_t, float* __restrict__ beta)
{
  int h = blockIdx.x, b = blockIdx.y;
  int n = valid[b];
  int tid = threadIdx.x;
  __shared__ float e_l[TT];
  __shared__ float red[64];
  const float* sc = scores + ((size_t)b*NH + h)*TT;
  float lmax = -1e30f;
  for (int t=tid; t<n; t+=256){ float v = sc[t]; e_l[t]=v; lmax = fmaxf(lmax, v); }
  float m = bredMax(lmax, red);
  float ls = 0.f, lb = 0.f;
  for (int t=tid; t<n; t+=256){
    float e = expf(e_l[t] - m);
    e_l[t] = e;
    ls += e;
    lb = fmaf(e, rs_a[(size_t)b*TT+t]*mu_a[(size_t)b*TT+t], lb);
  }
  float S  = bredSum(ls, red);
  float Bs = bredSum(lb, red);
  float inv = 1.f/S;
  for (int t=tid; t<n; t+=256)
    alpha_t[((size_t)b*TT + t)*NH + h] = e_l[t]*rs_a[(size_t)b*TT+t]*inv;
  if (tid == 0) beta[b*NH+h] = Bs*inv;
}

// ------------- K3: partial u accumulation (alpha staged in LDS) -------------
__global__ __launch_bounds__(512) void k_accum(
    const float* __restrict__ X, const float* __restrict__ alpha_t,
    const int* __restrict__ valid, float* __restrict__ part, int ct)
{
  int c = blockIdx.x, b = blockIdx.y;
  int tid = threadIdx.x;
  int t0 = c*ct;
  int tend = min(valid[b], t0 + ct);
  float ax[16], ay[16];
#pragma unroll
  for (int h=0;h<16;h++){ ax[h]=0.f; ay[h]=0.f; }
  __shared__ float4 at[2][256];   // 64 t x 16 h per buffer
  if (t0 < tend){
    const float2* xb = (const float2*)(X + (size_t)b*TT*DD);
    const float4* ab = (const float4*)(alpha_t + (size_t)b*TT*NH);
    int nsub = (tend - t0 + 63) >> 6;
    float4 nxt = make_float4(0.f,0.f,0.f,0.f);
    if (tid < 256) at[0][tid] = ab[(size_t)t0*4 + tid];
    for (int s=0; s<nsub; s++){
      if (s+1 < nsub && tid < 256) nxt = ab[(size_t)(t0+(s+1)*64)*4 + tid];
      __syncthreads();
      int ts = t0 + s*64;
      int te = min(tend - ts, 64);
      const float4* av = at[s&1];
      float2 xv = xb[(size_t)ts*(DD/2) + tid];
      for (int tl=0; tl<te; tl++){
        float2 xc = xv;
        if (tl+1 < te) xv = xb[(size_t)(ts+tl+1)*(DD/2) + tid];
        float4 q0 = av[tl*4+0], q1 = av[tl*4+1], q2 = av[tl*4+2], q3 = av[tl*4+3];
        float a[16] = {q0.x,q0.y,q0.z,q0.w, q1.x,q1.y,q1.z,q1.w,
                       q2.x,q2.y,q2.z,q2.w, q3.x,q3.y,q3.z,q3.w};
#pragma unroll
        for (int h=0;h<16;h++){
          ax[h] = fmaf(a[h], xc.x, ax[h]);
          ay[h] = fmaf(a[h], xc.y, ay[h]);
        }
      }
      if (s+1 < nsub){
        __syncthreads();
        if (tid < 256) at[(s+1)&1][tid] = nxt;
      }
    }
  }
  float* pp = part + (((size_t)c*BB + b)*NH)*DD;
#pragma unroll
  for (int h=0;h<16;h++)
    *(float2*)(pp + (size_t)h*DD + tid*2) = make_float2(ax[h], ay[h]);
}

// ------------- K4: reduce partials + finalize u -------------
__global__ __launch_bounds__(256) void k_ufin(const float* __restrict__ part,
   const float* __restrict__ beta, const float* __restrict__ g_kv,
   const float* __restrict__ b_kv, float* __restrict__ u, int nc)
{
  int h = blockIdx.x, b = blockIdx.y;
  int tid = threadIdx.x;
  int d = tid*4;
  float4 s = make_float4(0.f,0.f,0.f,0.f);
  for (int c=0;c<nc;c++){
    float4 v = *(const float4*)(part + (((size_t)c*BB + b)*NH + h)*DD + d);
    s.x+=v.x; s.y+=v.y; s.z+=v.z; s.w+=v.w;
  }
  float be = beta[b*NH+h];
  float4 g = *(const float4*)(g_kv + d);
  float4 bv = *(const float4*)(b_kv + d);
  float4 r;
  r.x = fmaf(g.x, s.x-be, bv.x);
  r.y = fmaf(g.y, s.y-be, bv.y);
  r.z = fmaf(g.z, s.z-be, bv.z);
  r.w = fmaf(g.w, s.w-be, bv.w);
  *(float4*)(u + ((size_t)b*NH + h)*DD + d) = r;
}

// ------------- K5a: ctx = Wv_h @ u + bv -------------
__global__ __launch_bounds__(256) void k_ctx(const float* __restrict__ u,
    const float* __restrict__ Wfull, const float* __restrict__ bfull,
    float* __restrict__ ctx)
{
  int h = blockIdx.x, b = blockIdx.y;
  int tid = threadIdx.x;
  __shared__ float ul[DD];
  __shared__ float Wl[64][65];
  __shared__ float red2[4][64];
  ((float4*)ul)[tid] = ((const float4*)(u + ((size_t)b*NH + h)*DD))[tid];
  int j = tid & 63, quart = tid >> 6;
  float acc = 0.f;
  const float* Wv = Wfull + (size_t)2*DD*DD;
  for (int dc=0; dc<DD; dc+=64){
#pragma unroll
    for (int p=0;p<4;p++){
      int fi = p*256 + tid, r = fi >> 4, q4 = fi & 15;
      float4 v = *(const float4*)(Wv + (size_t)(h*HDIM + r)*DD + dc + q4*4);
      Wl[r][q4*4+0]=v.x; Wl[r][q4*4+1]=v.y; Wl[r][q4*4+2]=v.z; Wl[r][q4*4+3]=v.w;
    }
    __syncthreads();
#pragma unroll
    for (int i=0;i<16;i++)
      acc = fmaf(Wl[j][quart*16+i], ul[dc + quart*16 + i], acc);
    __syncthreads();
  }
  red2[quart][j] = acc;
  __syncthreads();
  if (quart == 0){
    float v = red2[0][j] + red2[1][j] + red2[2][j] + red2[3][j];
    ctx[(size_t)b*DD + h*HDIM + j] = v + bfull[2*DD + h*HDIM + j];
  }
}

// ------------- K5c: out = LN(o + h_t) -------------
__global__ __launch_bounds__(256) void k_outln(const float* __restrict__ o,
   const float* __restrict__ h_t, const float* __restrict__ g,
   const float* __restrict__ bb, float* __restrict__ out)
{
  int b = blockIdx.x, tid = threadIdx.x;
  __shared__ float red[64];
  float4 a = ((const float4*)(o + (size_t)b*DD))[tid];
  float4 r = ((const float4*)(h_t + (size_t)b*DD))[tid];
  a.x+=r.x; a.y+=r.y; a.z+=r.z; a.w+=r.w;
  float s = a.x + a.y + a.z + a.w;
  s = bredSum(s, red);
  float mu = s * (1.f/DD);
  float d0=a.x-mu, d1=a.y-mu, d2=a.z-mu, d3=a.w-mu;
  float s2 = d0*d0 + d1*d1 + d2*d2 + d3*d3;
  s2 = bredSum(s2, red);
  float rs = rsqrtf(s2*(1.f/DD) + EPS);
  float4 gv = ((const float4*)g)[tid], bv = ((const float4*)bb)[tid];
  float4 ov;
  ov.x = fmaf(d0*rs, gv.x, bv.x);
  ov.y = fmaf(d1*rs, gv.y, bv.y);
  ov.z = fmaf(d2*rs, gv.z, bv.z);
  ov.w = fmaf(d3*rs, gv.w, bv.w);
  ((float4*)(out + (size_t)b*DD))[tid] = ov;
}

extern "C" void kernel_launch(void* const* d_in, const int* in_sizes, int n_in,
                              void* d_out, int out_size, void* d_ws, size_t ws_size,
                              hipStream_t stream) {
  const float* h_t     = (const float*)d_in[0];
  const float* H_p     = (const float*)d_in[1];
  const int*   valid   = (const int*)  d_in[2];
  const float* ln_q_g  = (const float*)d_in[3];
  const float* ln_q_b  = (const float*)d_in[4];
  const float* ln_kv_g = (const float*)d_in[5];
  const float* ln_kv_b = (const float*)d_in[6];
  const float* ln_out_g= (const float*)d_in[7];
  const float* ln_out_b= (const float*)d_in[8];
  const float* log_tau = (const float*)d_in[9];
  const float* in_w    = (const float*)d_in[10];
  const float* in_b    = (const float*)d_in[11];
  const float* out_w   = (const float*)d_in[12];
  const float* out_b   = (const float*)d_in[13];
  float* out = (float*)d_out;

  float* ws     = (float*)d_ws;
  float* q      = ws;
  float* qh     = q      + BB*DD;
  float* gs_t   = qh     + BB*DD;
  float* gsum   = gs_t   + (size_t)BB*DD*NH;
  float* cst    = gsum   + BB*NH;
  float* scores = cst    + BB*NH;
  float* mu_a   = scores + (size_t)BB*NH*TT;
  float* rs_a   = mu_a   + BB*TT;
  float* alpha  = rs_a   + BB*TT;
  float* beta   = alpha  + (size_t)BB*TT*NH;
  float* u      = beta   + BB*NH;
  float* ctx    = u      + (size_t)BB*NH*DD;
  float* o      = ctx    + BB*DD;
  float* part   = o      + BB*DD;
  // shared region "part": gemm partials (consumed before k_scores),
  // then pacc/pstat (consumed by k_sred before k_accum writes part).
  float4* pacc  = (float4*)part;                     // 4,194,304 floats
  float2* pstat = (float2*)(part + (size_t)4194304); //   524,288 floats

  size_t base_floats = (size_t)(part - ws);
  const size_t pacc_region = 4194304 + 524288;
  int nc = 16;
  size_t accum_region = (size_t)nc*BB*NH*DD;
  size_t region = accum_region > pacc_region ? accum_region : pacc_region;
  if ((base_floats + region) * sizeof(float) > ws_size){
    nc = 8;
    accum_region = (size_t)nc*BB*NH*DD;
    region = accum_region > pacc_region ? accum_region : pacc_region;
  }
  int ct = TT / nc;

  k_qln<<<BB, 256, 0, stream>>>(h_t, ln_q_g, ln_q_b, log_tau, q);
  k_gemmsplit<<<dim3(16,8), 256, 0, stream>>>(q, in_w, part);
  k_gemmred<<<BB, 256, 0, stream>>>(part, in_b, qh);
  k_prep_s<<<dim3(NH,BB), 256, 0, stream>>>(qh, in_w, in_b, ln_kv_g, ln_kv_b, gs_t, gsum, cst);
  k_scores<<<dim3((TT/SR)*DSPLIT,BB), 256, 0, stream>>>(H_p, valid, gs_t, pacc, pstat);
  k_sred<<<dim3(TT/64,BB), 256, 0, stream>>>(pacc, pstat, valid, gsum, cst, scores, mu_a, rs_a);
  k_softmax<<<dim3(NH,BB), 256, 0, stream>>>(scores, mu_a, rs_a, valid, alpha, beta);
  k_accum<<<dim3(nc,BB), 512, 0, stream>>>(H_p, alpha, valid, part, ct);
  k_ufin<<<dim3(NH,BB), 256, 0, stream>>>(part, beta, ln_kv_g, ln_kv_b, u, nc);
  k_ctx<<<dim3(NH,BB), 256, 0, stream>>>(u, in_w, in_b, ctx);
  k_gemmsplit<<<dim3(16,8), 256, 0, stream>>>(ctx, out_w, part);
  k_gemmred<<<BB, 256, 0, stream>>>(part, out_b, o);
  k_outln<<<BB, 256, 0, stream>>>(o, h_t, ln_out_g, ln_out_b, out);
}